// Round 2
// baseline (554.359 us; speedup 1.0000x reference)
//
#include <hip/hip_runtime.h>

typedef unsigned short u16;
typedef unsigned int u32;

#define NEG_SLOPE 0.2f

using short8 = __attribute__((ext_vector_type(8))) short;
using float4v = __attribute__((ext_vector_type(4))) float;

__device__ __forceinline__ float bfu(u16 v) { return __uint_as_float(((u32)v) << 16); }
__device__ __forceinline__ float bflo(u32 u) { return __uint_as_float(u << 16); }
__device__ __forceinline__ float bfhi(u32 u) { return __uint_as_float(u & 0xffff0000u); }
__device__ __forceinline__ u16 f2bf(float f) {
  u32 x = __float_as_uint(f);
  return (u16)((x + 0x7fffu + ((x >> 16) & 1u)) >> 16);
}
__device__ __forceinline__ float loadf(const void* p, int idx, int isbf) {
  return isbf ? bfu(((const u16*)p)[idx]) : ((const float*)p)[idx];
}

// physical XCD id (HW_REG_XCC_ID = 20, gfx940+; m09-verified). Wave-uniform SGPR.
__device__ __forceinline__ int xcc_id() {
  unsigned v;
  asm volatile("s_getreg_b32 %0, hwreg(20, 0, 8)" : "=s"(v));
  return (int)(v & 7u);
}

// ---------------- dtype detection (bf16 vs f32 inputs) ----------------
__global__ __launch_bounds__(256) void detect_dtype(const u32* __restrict__ w,
                                                    int nwords, int* __restrict__ flag) {
  __shared__ int cnt;
  if (threadIdx.x == 0) cnt = 0;
  __syncthreads();
  int c = 0;
  for (int i = threadIdx.x; i < nwords; i += 256) {
    u32 e = (w[i] >> 7) & 0xFFu;  // exponent of low-half-as-bf16
    c += (e >= 0x60u && e <= 0x90u) ? 1 : 0;
  }
  atomicAdd(&cnt, c);
  __syncthreads();
  if (threadIdx.x == 0) flag[0] = (cnt * 2 > nwords) ? 1 : 0;  // 1 = bf16
}

__global__ __launch_bounds__(256) void zero_i32(int* __restrict__ p, int n) {
  int i = blockIdx.x * 256 + threadIdx.x;
  if (i < n) p[i] = 0;
}

// ---------------- scans ----------------

// scan1 folds the 8 per-XCD histogram replicas:
//   reads cnt8[r*N+idx], writes back the per-replica exclusive offset (within node),
//   and scans the per-node total.
__global__ __launch_bounds__(256) void scan1(int* __restrict__ cnt8,
                                             int* __restrict__ indptr,
                                             int* __restrict__ bsum, int N) {
  __shared__ int sh[256];
  int t = threadIdx.x;
  int idx = blockIdx.x * 256 + t;
  int v = 0;
  if (idx < N) {
    int s = 0;
#pragma unroll
    for (int r = 0; r < 8; ++r) {
      int c = cnt8[r * N + idx];
      cnt8[r * N + idx] = s;  // exclusive offset of replica r within node idx
      s += c;
    }
    v = s;
  }
  sh[t] = v;
  __syncthreads();
  for (int off = 1; off < 256; off <<= 1) {
    int y = (t >= off) ? sh[t - off] : 0;
    __syncthreads();
    sh[t] += y;
    __syncthreads();
  }
  if (idx < N) indptr[idx] = sh[t] - v;  // exclusive, pre-offset
  if (t == 255) bsum[blockIdx.x] = sh[255];
}

// parallel single-block exclusive scan of block sums (NB <= 512)
__global__ __launch_bounds__(512) void scan2par(int* __restrict__ bsum, int NB) {
  __shared__ int sh[512];
  int t = threadIdx.x;
  int v = (t < NB) ? bsum[t] : 0;
  sh[t] = v;
  __syncthreads();
  for (int off = 1; off < 512; off <<= 1) {
    int y = (t >= off) ? sh[t - off] : 0;
    __syncthreads();
    sh[t] += y;
    __syncthreads();
  }
  if (t < NB) bsum[t] = sh[t] - v;  // exclusive
}

__global__ __launch_bounds__(256) void scan3(int* __restrict__ indptr,
                                             const int* __restrict__ boff,
                                             int N, int E) {
  int idx = blockIdx.x * 256 + threadIdx.x;
  if (idx < N) indptr[idx] += boff[blockIdx.x];
  if (idx == 0) indptr[N] = E;
}

// ---------------- scatter without atomics (uses precomputed replica+rank) --------
__global__ __launch_bounds__(256) void scatter2(const int* __restrict__ src,
                                                const int* __restrict__ dst,
                                                const int* __restrict__ rank,
                                                const int* __restrict__ indptr,
                                                const int* __restrict__ cnt8,
                                                int* __restrict__ ssrc, int E, int N) {
  int e = blockIdx.x * 256 + threadIdx.x;
  if (e < E) {
    int d = dst[e];
    u32 rk = (u32)rank[e];
    int rep = (int)(rk >> 28);
    int lr = (int)(rk & 0x0FFFFFFFu);
    ssrc[indptr[d] + cnt8[rep * N + d] + lr] = src[e];
  }
}

// ---------------- histogram + rank (standalone for attribution) ----------------
// Per-XCD replicated counters; inline-asm global_atomic_add with sc0 (return old)
// and NO sc1 -> RMW performed at the XCD-local L2 (the nearest coherent point).
// Correct because replica r is only ever touched from physical XCD r, and the
// implicit end-of-dispatch release makes the dirty L2 lines visible to scan1.
__global__ __launch_bounds__(256) void hist_kernel(const int* __restrict__ dst,
                                                   int* __restrict__ cnt8,
                                                   int* __restrict__ rank, int E, int N) {
  int base = blockIdx.x * 1024 + (int)threadIdx.x * 4;
  int rep = xcc_id();
  int* cbase = cnt8 + rep * N;
  int rt = rep << 28;
  int one = 1;
  if (base + 3 < E) {
    int4 dv = *(const int4*)(dst + base);
    int* p0 = &cbase[dv.x];
    int* p1 = &cbase[dv.y];
    int* p2 = &cbase[dv.z];
    int* p3 = &cbase[dv.w];
    int r0, r1, r2, r3;
    asm volatile(
        "global_atomic_add %0, %4, %8, off sc0\n\t"
        "global_atomic_add %1, %5, %8, off sc0\n\t"
        "global_atomic_add %2, %6, %8, off sc0\n\t"
        "global_atomic_add %3, %7, %8, off sc0\n\t"
        "s_waitcnt vmcnt(0)"
        : "=&v"(r0), "=&v"(r1), "=&v"(r2), "=&v"(r3)
        : "v"(p0), "v"(p1), "v"(p2), "v"(p3), "v"(one)
        : "memory");
    *(int4*)(rank + base) = make_int4(r0 | rt, r1 | rt, r2 | rt, r3 | rt);
  } else {
    for (int j = 0; j < 4; ++j) {
      int e = base + j;
      if (e < E) {
        int* pp = &cbase[dst[e]];
        int old;
        asm volatile(
            "global_atomic_add %0, %1, %2, off sc0\n\t"
            "s_waitcnt vmcnt(0)"
            : "=&v"(old)
            : "v"(pp), "v"(one)
            : "memory");
        rank[e] = rt | old;
      }
    }
  }
}

// ---------------- B-fragment swizzle buffer ----------------
__global__ __launch_bounds__(256) void bsw_build(const void* __restrict__ W,
                                                 u16* __restrict__ Bsw, int K,
                                                 const int* __restrict__ dflag) {
  const int isbf = dflag[0];
  int t = blockIdx.x * 256 + threadIdx.x;
  int total = (K / 32) * 8 * 64;
  if (t >= total) return;
  int lane = t & 63;
  int c = (t >> 6) & 7;
  int ktile = t >> 9;
  int n = lane & 15, q = lane >> 4;
  int col = c * 16 + n;
  u16 vals[8];
#pragma unroll
  for (int j = 0; j < 8; ++j) {
    int k = ktile * 32 + q * 8 + j;
    int idx = col * K + k;
    vals[j] = isbf ? ((const u16*)W)[idx] : f2bf(((const float*)W)[idx]);
  }
  *(uint4*)(Bsw + (size_t)t * 8) = *(uint4*)vals;
}

// ---------------- MFMA GEMM body (device fn) + fused el/er epilogue ----------------
template <int K, int DYNA>
__device__ __forceinline__ void gemm_body(int bix, const void* __restrict__ Xv,
                                          const u16* __restrict__ Bsw,
                                          u16* __restrict__ Hb,
                                          const void* __restrict__ al,
                                          const void* __restrict__ ar,
                                          float* __restrict__ el_,
                                          float* __restrict__ er_, int N,
                                          const int* __restrict__ dflag) {
  const int isbfP = dflag[0];
  const int isbfA = DYNA ? isbfP : 1;  // x intermediate is always bf16
  int tid = threadIdx.x;
  int w = tid >> 6, lane = tid & 63;
  int n = lane & 15, q = lane >> 4;
  int row0 = bix * 64 + w * 16;
  int m = row0 + n;
  int mclamp = (m < N) ? m : 0;

  float alv[8], arv[8];
#pragma unroll
  for (int c = 0; c < 8; ++c) {
    alv[c] = loadf(al, c * 16 + n, isbfP);
    arv[c] = loadf(ar, c * 16 + n, isbfP);
  }

  float4v acc[8];
#pragma unroll
  for (int c = 0; c < 8; ++c) acc[c] = (float4v){0.f, 0.f, 0.f, 0.f};

#pragma unroll
  for (int t = 0; t < K / 32; ++t) {
    short8 af;
    if (isbfA) {
      af = *(const short8*)((const u16*)Xv + (size_t)mclamp * K + t * 32 + q * 8);
    } else {
      const float* Af = (const float*)Xv + (size_t)mclamp * K + t * 32 + q * 8;
      float4 f0 = *(const float4*)Af;
      float4 f1 = *(const float4*)(Af + 4);
      u16 tmp[8] = {f2bf(f0.x), f2bf(f0.y), f2bf(f0.z), f2bf(f0.w),
                    f2bf(f1.x), f2bf(f1.y), f2bf(f1.z), f2bf(f1.w)};
      af = *(short8*)tmp;
    }
    const uint4* bt = (const uint4*)Bsw + ((size_t)t * 8) * 64 + lane;
#pragma unroll
    for (int c = 0; c < 8; ++c) {
      uint4 bw = bt[c * 64];
      short8 bf = *(short8*)&bw;
      acc[c] = __builtin_amdgcn_mfma_f32_16x16x32_bf16(af, bf, acc[c], 0, 0, 0);
    }
  }

  // Hb store: D layout col = c*16 + (lane&15), row = row0 + q*4 + r
  // (direct u16 stores; L2 merges them into full lines — verified round 1:
  //  LDS-bounce coalescing left WRITE_SIZE byte-identical and cost +7us)
#pragma unroll
  for (int c = 0; c < 8; ++c) {
#pragma unroll
    for (int r = 0; r < 4; ++r) {
      int row = row0 + q * 4 + r;
      if (row < N) Hb[(size_t)row * 128 + c * 16 + n] = f2bf(acc[c][r]);
    }
  }

  // fused el/er: reduce across the 16 lanes of each quad-row group
#pragma unroll
  for (int r = 0; r < 4; ++r) {
    float sl = 0.f, sr = 0.f;
#pragma unroll
    for (int c = 0; c < 8; ++c) {
      float v = acc[c][r];
      sl = fmaf(v, alv[c], sl);
      sr = fmaf(v, arv[c], sr);
    }
#pragma unroll
    for (int off = 1; off < 16; off <<= 1) {
      sl += __shfl_xor(sl, off);
      sr += __shfl_xor(sr, off);
    }
    if (n == 0) {
      int row = row0 + q * 4 + r;
      if (row < N) {
        el_[row] = sl;
        er_[row] = sr;
      }
    }
  }
}

template <int K, int DYNA>
__global__ __launch_bounds__(256) void gemm_mfma(const void* __restrict__ Xv,
                                                 const u16* __restrict__ Bsw,
                                                 u16* __restrict__ Hb,
                                                 const void* __restrict__ al,
                                                 const void* __restrict__ ar,
                                                 float* __restrict__ el_,
                                                 float* __restrict__ er_, int N,
                                                 const int* __restrict__ dflag) {
  gemm_body<K, DYNA>(blockIdx.x, Xv, Bsw, Hb, al, ar, el_, er_, N, dflag);
}

// ---------------- aggregation: one wave per dst, 4-stream online softmax ----------
template <int MODE>
__global__ __launch_bounds__(256) void agg_kernel(const u32* __restrict__ Hb,
                                                  const float* __restrict__ el,
                                                  const float* __restrict__ er,
                                                  const int* __restrict__ indptr,
                                                  const int* __restrict__ ssrc,
                                                  const void* __restrict__ bias,
                                                  void* __restrict__ outv, int N,
                                                  const int* __restrict__ dflag) {
  const int isbf = dflag[0];
  int tid = threadIdx.x;
  int n = blockIdx.x * 4 + (tid >> 6);
  int lane = tid & 63;
  if (n >= N) return;

  int beg = indptr[n];
  int end = indptr[n + 1];
  float ern = er[n];

  float ms[4], ll[4], aa0[4], aa1[4];
#pragma unroll
  for (int j = 0; j < 4; ++j) {
    ms[j] = -INFINITY; ll[j] = 0.f; aa0[j] = 0.f; aa1[j] = 0.f;
  }

  int p = beg;
  int id[8];
#pragma unroll
  for (int j = 0; j < 8; ++j) id[j] = (p + j < end) ? ssrc[p + j] : 0;
  float ev[4];
  u32 hv[4];
#pragma unroll
  for (int j = 0; j < 4; ++j) {
    ev[j] = el[id[j]];
    hv[j] = Hb[(size_t)id[j] * 64 + lane];
  }

  for (; p < end; p += 4) {
    float ev2[4];
    u32 hv2[4];
#pragma unroll
    for (int j = 0; j < 4; ++j) {
      ev2[j] = el[id[4 + j]];
      hv2[j] = Hb[(size_t)id[4 + j] * 64 + lane];
    }
    int idn[4];
#pragma unroll
    for (int j = 0; j < 4; ++j) idn[j] = (p + 8 + j < end) ? ssrc[p + 8 + j] : 0;

#pragma unroll
    for (int j = 0; j < 4; ++j) {
      if (p + j < end) {
        float sc = ev[j] + ern;
        sc = (sc > 0.f) ? sc : NEG_SLOPE * sc;
        float mn = fmaxf(ms[j], sc);
        float corr = __expf(ms[j] - mn), pe = __expf(sc - mn);
        ll[j] = ll[j] * corr + pe;
        aa0[j] = aa0[j] * corr + pe * bflo(hv[j]);
        aa1[j] = aa1[j] * corr + pe * bfhi(hv[j]);
        ms[j] = mn;
      }
    }
#pragma unroll
    for (int j = 0; j < 4; ++j) {
      id[j] = id[4 + j];
      id[4 + j] = idn[j];
      ev[j] = ev2[j];
      hv[j] = hv2[j];
    }
  }

  float mm = fmaxf(fmaxf(ms[0], ms[1]), fmaxf(ms[2], ms[3]));
  float msafe = (mm > -INFINITY) ? mm : 0.f;
  float l = 0.f, a0 = 0.f, a1 = 0.f;
#pragma unroll
  for (int j = 0; j < 4; ++j) {
    float c = __expf(ms[j] - msafe);
    l += ll[j] * c;
    a0 += aa0[j] * c;
    a1 += aa1[j] * c;
  }
  float inv = (l > 0.f) ? 1.f / l : 0.f;
  float o0 = a0 * inv + loadf(bias, 2 * lane, isbf);
  float o1 = a1 * inv + loadf(bias, 2 * lane + 1, isbf);

  if (MODE == 0) {
    o0 = (o0 > 0.f) ? o0 : (__expf(o0) - 1.f);
    o1 = (o1 > 0.f) ? o1 : (__expf(o1) - 1.f);
    ((u32*)outv)[(size_t)n * 64 + lane] = (u32)f2bf(o0) | ((u32)f2bf(o1) << 16);
  } else {
    if (isbf) {
      ((u32*)outv)[(size_t)n * 64 + lane] = (u32)f2bf(o0) | ((u32)f2bf(o1) << 16);
    } else {
      ((float2*)outv)[(size_t)n * 64 + lane] = make_float2(o0, o1);
    }
  }
}

// ---------------- launch ----------------

extern "C" void kernel_launch(void* const* d_in, const int* in_sizes, int n_in,
                              void* d_out, int out_size, void* d_ws, size_t ws_size,
                              hipStream_t stream) {
  const int IN_FEATS = 256, HID = 128;
  const void* features = d_in[0];
  const int* src = (const int*)d_in[1];
  const int* dst = (const int*)d_in[2];
  const void* W1 = d_in[3];
  const void* al1 = d_in[4];
  const void* ar1 = d_in[5];
  const void* b1 = d_in[6];
  const void* W2 = d_in[7];
  const void* al2 = d_in[8];
  const void* ar2 = d_in[9];
  const void* b2 = d_in[10];

  const int N = in_sizes[0] / IN_FEATS;  // 100000
  const int E = in_sizes[1];             // 1600000

  char* p = (char*)d_ws;
  auto alloc = [&](size_t bytes) -> void* {
    void* q = (void*)p;
    p += (bytes + 255) & ~(size_t)255;
    return q;
  };
  int* dflag = (int*)alloc(256);
  u16* Bsw1 = (u16*)alloc((size_t)(IN_FEATS / 32) * 8 * 64 * 8 * 2);  // 64 KB
  u16* Bsw2 = (u16*)alloc((size_t)(HID / 32) * 8 * 64 * 8 * 2);       // 32 KB
  u16* hb = (u16*)alloc((size_t)N * HID * 2);  // 25.6 MB
  u16* x = (u16*)alloc((size_t)N * HID * 2);   // 25.6 MB
  float* el = (float*)alloc((size_t)N * 4);
  float* er = (float*)alloc((size_t)N * 4);
  int* cnt8 = (int*)alloc((size_t)8 * N * 4);  // 3.2 MB (8 per-XCD replicas)
  int* indptr = (int*)alloc((size_t)(N + 1) * 4);
  int* rank = (int*)alloc((size_t)E * 4);      // 6.4 MB
  int* bsum = (int*)alloc((size_t)((N + 255) / 256) * 4);
  int* ssrc = (int*)alloc((size_t)E * 4);

  const int NB = (N + 255) / 256;     // 391 (<= 512 for scan2par)
  const int EB = (E + 255) / 256;     // 6250
  const int HEB = (E + 1023) / 1024;  // 1563 (hist: 4 edges/thread)
  const int GEMM_B = (N + 63) / 64;   // 1563
  const int NODE_B = (N + 3) / 4;     // 25000

  detect_dtype<<<1, 256, 0, stream>>>((const u32*)features, 4096, dflag);
  zero_i32<<<(8 * N + 255) / 256, 256, 0, stream>>>(cnt8, 8 * N);
  bsw_build<<<((IN_FEATS / 32) * 8 * 64 + 255) / 256, 256, 0, stream>>>(W1, Bsw1, IN_FEATS, dflag);
  bsw_build<<<((HID / 32) * 8 * 64 + 255) / 256, 256, 0, stream>>>(W2, Bsw2, HID, dflag);

  // De-fused for per-kernel attribution (round 2 ablation): GEMM layer 1, then hist.
  gemm_mfma<IN_FEATS, 1><<<GEMM_B, 256, 0, stream>>>(features, Bsw1, hb, al1, ar1, el, er, N, dflag);
  hist_kernel<<<HEB, 256, 0, stream>>>(dst, cnt8, rank, E, N);

  scan1<<<NB, 256, 0, stream>>>(cnt8, indptr, bsum, N);
  scan2par<<<1, 512, 0, stream>>>(bsum, NB);
  scan3<<<NB, 256, 0, stream>>>(indptr, bsum, N, E);
  scatter2<<<EB, 256, 0, stream>>>(src, dst, rank, indptr, cnt8, ssrc, E, N);

  agg_kernel<0><<<NODE_B, 256, 0, stream>>>((const u32*)hb, el, er, indptr, ssrc, b1, (void*)x, N, dflag);

  gemm_mfma<HID, 0><<<GEMM_B, 256, 0, stream>>>((const void*)x, Bsw2, hb, al2, ar2, el, er, N, dflag);
  agg_kernel<1><<<NODE_B, 256, 0, stream>>>((const u32*)hb, el, er, indptr, ssrc, b2, d_out, N, dflag);
}

// Round 3
// 488.775 us; speedup vs baseline: 1.1342x; 1.1342x over previous
//
#include <hip/hip_runtime.h>

typedef unsigned short u16;
typedef unsigned int u32;

#define NEG_SLOPE 0.2f

using short8 = __attribute__((ext_vector_type(8))) short;
using float4v = __attribute__((ext_vector_type(4))) float;

__device__ __forceinline__ float bfu(u16 v) { return __uint_as_float(((u32)v) << 16); }
__device__ __forceinline__ float bflo(u32 u) { return __uint_as_float(u << 16); }
__device__ __forceinline__ float bfhi(u32 u) { return __uint_as_float(u & 0xffff0000u); }
__device__ __forceinline__ u16 f2bf(float f) {
  u32 x = __float_as_uint(f);
  return (u16)((x + 0x7fffu + ((x >> 16) & 1u)) >> 16);
}
__device__ __forceinline__ float loadf(const void* p, int idx, int isbf) {
  return isbf ? bfu(((const u16*)p)[idx]) : ((const float*)p)[idx];
}

// physical XCD id (HW_REG_XCC_ID = 20, gfx940+; m09-verified). Wave-uniform SGPR.
__device__ __forceinline__ int xcc_id() {
  unsigned v;
  asm volatile("s_getreg_b32 %0, hwreg(20, 0, 8)" : "=s"(v));
  return (int)(v & 7u);
}

// ---------------- dtype detection (bf16 vs f32 inputs) ----------------
__global__ __launch_bounds__(256) void detect_dtype(const u32* __restrict__ w,
                                                    int nwords, int* __restrict__ flag) {
  __shared__ int cnt;
  if (threadIdx.x == 0) cnt = 0;
  __syncthreads();
  int c = 0;
  for (int i = threadIdx.x; i < nwords; i += 256) {
    u32 e = (w[i] >> 7) & 0xFFu;  // exponent of low-half-as-bf16
    c += (e >= 0x60u && e <= 0x90u) ? 1 : 0;
  }
  atomicAdd(&cnt, c);
  __syncthreads();
  if (threadIdx.x == 0) flag[0] = (cnt * 2 > nwords) ? 1 : 0;  // 1 = bf16
}

__global__ __launch_bounds__(256) void zero_i32(int* __restrict__ p, int n) {
  int i = blockIdx.x * 256 + threadIdx.x;
  if (i < n) p[i] = 0;
}

// ---------------- scans ----------------

// scan1 folds the 8 per-XCD histogram replicas:
//   reads cnt8[r*N+idx], writes back the per-replica exclusive offset (within node),
//   and scans the per-node total.
__global__ __launch_bounds__(256) void scan1(int* __restrict__ cnt8,
                                             int* __restrict__ indptr,
                                             int* __restrict__ bsum, int N) {
  __shared__ int sh[256];
  int t = threadIdx.x;
  int idx = blockIdx.x * 256 + t;
  int v = 0;
  if (idx < N) {
    int s = 0;
#pragma unroll
    for (int r = 0; r < 8; ++r) {
      int c = cnt8[r * N + idx];
      cnt8[r * N + idx] = s;  // exclusive offset of replica r within node idx
      s += c;
    }
    v = s;
  }
  sh[t] = v;
  __syncthreads();
  for (int off = 1; off < 256; off <<= 1) {
    int y = (t >= off) ? sh[t - off] : 0;
    __syncthreads();
    sh[t] += y;
    __syncthreads();
  }
  if (idx < N) indptr[idx] = sh[t] - v;  // exclusive, pre-offset
  if (t == 255) bsum[blockIdx.x] = sh[255];
}

// parallel single-block exclusive scan of block sums (NB <= 512)
__global__ __launch_bounds__(512) void scan2par(int* __restrict__ bsum, int NB) {
  __shared__ int sh[512];
  int t = threadIdx.x;
  int v = (t < NB) ? bsum[t] : 0;
  sh[t] = v;
  __syncthreads();
  for (int off = 1; off < 512; off <<= 1) {
    int y = (t >= off) ? sh[t - off] : 0;
    __syncthreads();
    sh[t] += y;
    __syncthreads();
  }
  if (t < NB) bsum[t] = sh[t] - v;  // exclusive
}

__global__ __launch_bounds__(256) void scan3(int* __restrict__ indptr,
                                             const int* __restrict__ boff,
                                             int N, int E) {
  int idx = blockIdx.x * 256 + threadIdx.x;
  if (idx < N) indptr[idx] += boff[blockIdx.x];
  if (idx == 0) indptr[N] = E;
}

// ---------------- scatter without atomics (uses precomputed replica+rank) --------
__global__ __launch_bounds__(256) void scatter2(const int* __restrict__ src,
                                                const int* __restrict__ dst,
                                                const int* __restrict__ rank,
                                                const int* __restrict__ indptr,
                                                const int* __restrict__ cnt8,
                                                int* __restrict__ ssrc, int E, int N) {
  int e = blockIdx.x * 256 + threadIdx.x;
  if (e < E) {
    int d = dst[e];
    u32 rk = (u32)rank[e];
    int rep = (int)(rk >> 28);
    int lr = (int)(rk & 0x0FFFFFFFu);
    ssrc[indptr[d] + cnt8[rep * N + d] + lr] = src[e];
  }
}

// ---------------- B-fragment swizzle buffer ----------------
__global__ __launch_bounds__(256) void bsw_build(const void* __restrict__ W,
                                                 u16* __restrict__ Bsw, int K,
                                                 const int* __restrict__ dflag) {
  const int isbf = dflag[0];
  int t = blockIdx.x * 256 + threadIdx.x;
  int total = (K / 32) * 8 * 64;
  if (t >= total) return;
  int lane = t & 63;
  int c = (t >> 6) & 7;
  int ktile = t >> 9;
  int n = lane & 15, q = lane >> 4;
  int col = c * 16 + n;
  u16 vals[8];
#pragma unroll
  for (int j = 0; j < 8; ++j) {
    int k = ktile * 32 + q * 8 + j;
    int idx = col * K + k;
    vals[j] = isbf ? ((const u16*)W)[idx] : f2bf(((const float*)W)[idx]);
  }
  *(uint4*)(Bsw + (size_t)t * 8) = *(uint4*)vals;
}

// ---------------- MFMA GEMM body (device fn) + fused el/er epilogue ----------------
template <int K, int DYNA>
__device__ __forceinline__ void gemm_body(int bix, const void* __restrict__ Xv,
                                          const u16* __restrict__ Bsw,
                                          u16* __restrict__ Hb,
                                          const void* __restrict__ al,
                                          const void* __restrict__ ar,
                                          float* __restrict__ el_,
                                          float* __restrict__ er_, int N,
                                          const int* __restrict__ dflag) {
  const int isbfP = dflag[0];
  const int isbfA = DYNA ? isbfP : 1;  // x intermediate is always bf16
  int tid = threadIdx.x;
  int w = tid >> 6, lane = tid & 63;
  int n = lane & 15, q = lane >> 4;
  int row0 = bix * 64 + w * 16;
  int m = row0 + n;
  int mclamp = (m < N) ? m : 0;

  float alv[8], arv[8];
#pragma unroll
  for (int c = 0; c < 8; ++c) {
    alv[c] = loadf(al, c * 16 + n, isbfP);
    arv[c] = loadf(ar, c * 16 + n, isbfP);
  }

  float4v acc[8];
#pragma unroll
  for (int c = 0; c < 8; ++c) acc[c] = (float4v){0.f, 0.f, 0.f, 0.f};

#pragma unroll
  for (int t = 0; t < K / 32; ++t) {
    short8 af;
    if (isbfA) {
      af = *(const short8*)((const u16*)Xv + (size_t)mclamp * K + t * 32 + q * 8);
    } else {
      const float* Af = (const float*)Xv + (size_t)mclamp * K + t * 32 + q * 8;
      float4 f0 = *(const float4*)Af;
      float4 f1 = *(const float4*)(Af + 4);
      u16 tmp[8] = {f2bf(f0.x), f2bf(f0.y), f2bf(f0.z), f2bf(f0.w),
                    f2bf(f1.x), f2bf(f1.y), f2bf(f1.z), f2bf(f1.w)};
      af = *(short8*)tmp;
    }
    const uint4* bt = (const uint4*)Bsw + ((size_t)t * 8) * 64 + lane;
#pragma unroll
    for (int c = 0; c < 8; ++c) {
      uint4 bw = bt[c * 64];
      short8 bf = *(short8*)&bw;
      acc[c] = __builtin_amdgcn_mfma_f32_16x16x32_bf16(af, bf, acc[c], 0, 0, 0);
    }
  }

  // Hb store: D layout col = c*16 + (lane&15), row = row0 + q*4 + r
  // (direct u16 stores; L2 merges them into full lines — verified round 1:
  //  LDS-bounce coalescing left WRITE_SIZE byte-identical and cost +7us)
#pragma unroll
  for (int c = 0; c < 8; ++c) {
#pragma unroll
    for (int r = 0; r < 4; ++r) {
      int row = row0 + q * 4 + r;
      if (row < N) Hb[(size_t)row * 128 + c * 16 + n] = f2bf(acc[c][r]);
    }
  }

  // fused el/er: reduce across the 16 lanes of each quad-row group
#pragma unroll
  for (int r = 0; r < 4; ++r) {
    float sl = 0.f, sr = 0.f;
#pragma unroll
    for (int c = 0; c < 8; ++c) {
      float v = acc[c][r];
      sl = fmaf(v, alv[c], sl);
      sr = fmaf(v, arv[c], sr);
    }
#pragma unroll
    for (int off = 1; off < 16; off <<= 1) {
      sl += __shfl_xor(sl, off);
      sr += __shfl_xor(sr, off);
    }
    if (n == 0) {
      int row = row0 + q * 4 + r;
      if (row < N) {
        el_[row] = sl;
        er_[row] = sr;
      }
    }
  }
}

template <int K, int DYNA>
__global__ __launch_bounds__(256) void gemm_mfma(const void* __restrict__ Xv,
                                                 const u16* __restrict__ Bsw,
                                                 u16* __restrict__ Hb,
                                                 const void* __restrict__ al,
                                                 const void* __restrict__ ar,
                                                 float* __restrict__ el_,
                                                 float* __restrict__ er_, int N,
                                                 const int* __restrict__ dflag) {
  gemm_body<K, DYNA>(blockIdx.x, Xv, Bsw, Hb, al, ar, el_, er_, N, dflag);
}

// fused: blocks [0, gemm_blocks) do GEMM layer 1; the rest do hist+rank.
// hist: per-XCD replicated counters; inline-asm global_atomic_add with sc0
// (return old) and NO sc1 -> RMW at the XCD-local L2. Correct because replica r
// is only touched from physical XCD r; end-of-dispatch release publishes to scan1.
template <int K, int DYNA>
__global__ __launch_bounds__(256) void fused_gemm_hist(
    const void* __restrict__ Xv, const u16* __restrict__ Bsw, u16* __restrict__ Hb,
    const void* __restrict__ al, const void* __restrict__ ar,
    float* __restrict__ el_, float* __restrict__ er_, int N,
    const int* __restrict__ dflag, int gemm_blocks,
    const int* __restrict__ dst, int* __restrict__ cnt8,
    int* __restrict__ rank, int E) {
  int bix = (int)blockIdx.x;
  if (bix < gemm_blocks) {
    gemm_body<K, DYNA>(bix, Xv, Bsw, Hb, al, ar, el_, er_, N, dflag);
    return;
  }
  int base = (bix - gemm_blocks) * 1024 + (int)threadIdx.x * 4;
  int rep = xcc_id();
  int* cbase = cnt8 + rep * N;
  int rt = rep << 28;
  int one = 1;
  if (base + 3 < E) {
    int4 dv = *(const int4*)(dst + base);
    int* p0 = &cbase[dv.x];
    int* p1 = &cbase[dv.y];
    int* p2 = &cbase[dv.z];
    int* p3 = &cbase[dv.w];
    int r0, r1, r2, r3;
    asm volatile(
        "global_atomic_add %0, %4, %8, off sc0\n\t"
        "global_atomic_add %1, %5, %8, off sc0\n\t"
        "global_atomic_add %2, %6, %8, off sc0\n\t"
        "global_atomic_add %3, %7, %8, off sc0\n\t"
        "s_waitcnt vmcnt(0)"
        : "=&v"(r0), "=&v"(r1), "=&v"(r2), "=&v"(r3)
        : "v"(p0), "v"(p1), "v"(p2), "v"(p3), "v"(one)
        : "memory");
    *(int4*)(rank + base) = make_int4(r0 | rt, r1 | rt, r2 | rt, r3 | rt);
  } else {
    for (int j = 0; j < 4; ++j) {
      int e = base + j;
      if (e < E) {
        int* pp = &cbase[dst[e]];
        int old;
        asm volatile(
            "global_atomic_add %0, %1, %2, off sc0\n\t"
            "s_waitcnt vmcnt(0)"
            : "=&v"(old)
            : "v"(pp), "v"(one)
            : "memory");
        rank[e] = rt | old;
      }
    }
  }
}

// ---------------- aggregation v2: two-phase wave-parallel softmax ----------------
// One wave per dst node. Phase 1: up to 64 edges scored lane-parallel (one
// coalesced ssrc load, one el gather, ONE v_exp for the whole chunk, shfl-tree
// max and sum). Phase 2: broadcast (id_e, pe_e) from lane e via readlane (SGPR,
// scalar addressing) and accumulate aa += pe_e * Hb[id_e] — 2 FMA/edge/lane.
// Normalization by l happens once at the end. Chunk loop handles degree > 64
// with a single rescale per chunk.
template <int MODE>
__global__ __launch_bounds__(256) void agg_kernel(const u32* __restrict__ Hb,
                                                  const float* __restrict__ el,
                                                  const float* __restrict__ er,
                                                  const int* __restrict__ indptr,
                                                  const int* __restrict__ ssrc,
                                                  const void* __restrict__ bias,
                                                  void* __restrict__ outv, int N,
                                                  const int* __restrict__ dflag) {
  const int isbf = dflag[0];
  int tid = threadIdx.x;
  int n = blockIdx.x * 4 + (tid >> 6);
  int lane = tid & 63;
  if (n >= N) return;

  int beg = indptr[n];
  int end = indptr[n + 1];
  float ern = er[n];

  float aa0 = 0.f, aa1 = 0.f;
  float m_run = -INFINITY, l_run = 0.f;

  for (int p = beg; p < end; p += 64) {
    int rem = end - p;  // >= 1
    int valid = lane < rem;
    int ide = valid ? ssrc[p + lane] : 0;

    // lane-parallel scores
    float sc = el[ide] + ern;
    sc = (sc > 0.f) ? sc : NEG_SLOPE * sc;
    sc = valid ? sc : -INFINITY;

    // wave max
    float mc = sc;
#pragma unroll
    for (int off = 1; off < 64; off <<= 1) mc = fmaxf(mc, __shfl_xor(mc, off));

    float m_new = fmaxf(m_run, mc);
    float corr = __expf(m_run - m_new);  // first chunk: exp(-inf)=0
    float pe = __expf(sc - m_new);       // invalid lanes: exp(-inf)=0

    // wave sum of pe
    float ls = pe;
#pragma unroll
    for (int off = 1; off < 64; off <<= 1) ls += __shfl_xor(ls, off);

    l_run = l_run * corr + ls;
    aa0 *= corr;
    aa1 *= corr;
    m_run = m_new;

    // phase 2: gather-accumulate, 4-deep unroll for MLP
    int cl = (rem < 64) ? rem : 64;
    int e = 0;
    for (; e + 4 <= cl; e += 4) {
      int i0 = __builtin_amdgcn_readlane(ide, e);
      int i1 = __builtin_amdgcn_readlane(ide, e + 1);
      int i2 = __builtin_amdgcn_readlane(ide, e + 2);
      int i3 = __builtin_amdgcn_readlane(ide, e + 3);
      u32 h0 = Hb[(size_t)i0 * 64 + lane];
      u32 h1 = Hb[(size_t)i1 * 64 + lane];
      u32 h2 = Hb[(size_t)i2 * 64 + lane];
      u32 h3 = Hb[(size_t)i3 * 64 + lane];
      float p0 = __int_as_float(__builtin_amdgcn_readlane(__float_as_int(pe), e));
      float p1 = __int_as_float(__builtin_amdgcn_readlane(__float_as_int(pe), e + 1));
      float p2 = __int_as_float(__builtin_amdgcn_readlane(__float_as_int(pe), e + 2));
      float p3 = __int_as_float(__builtin_amdgcn_readlane(__float_as_int(pe), e + 3));
      aa0 = fmaf(p0, bflo(h0), aa0);
      aa1 = fmaf(p0, bfhi(h0), aa1);
      aa0 = fmaf(p1, bflo(h1), aa0);
      aa1 = fmaf(p1, bfhi(h1), aa1);
      aa0 = fmaf(p2, bflo(h2), aa0);
      aa1 = fmaf(p2, bfhi(h2), aa1);
      aa0 = fmaf(p3, bflo(h3), aa0);
      aa1 = fmaf(p3, bfhi(h3), aa1);
    }
    for (; e < cl; ++e) {
      int i0 = __builtin_amdgcn_readlane(ide, e);
      u32 h0 = Hb[(size_t)i0 * 64 + lane];
      float p0 = __int_as_float(__builtin_amdgcn_readlane(__float_as_int(pe), e));
      aa0 = fmaf(p0, bflo(h0), aa0);
      aa1 = fmaf(p0, bfhi(h0), aa1);
    }
  }

  float inv = (l_run > 0.f) ? 1.f / l_run : 0.f;
  float o0 = aa0 * inv + loadf(bias, 2 * lane, isbf);
  float o1 = aa1 * inv + loadf(bias, 2 * lane + 1, isbf);

  if (MODE == 0) {
    o0 = (o0 > 0.f) ? o0 : (__expf(o0) - 1.f);
    o1 = (o1 > 0.f) ? o1 : (__expf(o1) - 1.f);
    ((u32*)outv)[(size_t)n * 64 + lane] = (u32)f2bf(o0) | ((u32)f2bf(o1) << 16);
  } else {
    if (isbf) {
      ((u32*)outv)[(size_t)n * 64 + lane] = (u32)f2bf(o0) | ((u32)f2bf(o1) << 16);
    } else {
      ((float2*)outv)[(size_t)n * 64 + lane] = make_float2(o0, o1);
    }
  }
}

// ---------------- launch ----------------

extern "C" void kernel_launch(void* const* d_in, const int* in_sizes, int n_in,
                              void* d_out, int out_size, void* d_ws, size_t ws_size,
                              hipStream_t stream) {
  const int IN_FEATS = 256, HID = 128;
  const void* features = d_in[0];
  const int* src = (const int*)d_in[1];
  const int* dst = (const int*)d_in[2];
  const void* W1 = d_in[3];
  const void* al1 = d_in[4];
  const void* ar1 = d_in[5];
  const void* b1 = d_in[6];
  const void* W2 = d_in[7];
  const void* al2 = d_in[8];
  const void* ar2 = d_in[9];
  const void* b2 = d_in[10];

  const int N = in_sizes[0] / IN_FEATS;  // 100000
  const int E = in_sizes[1];             // 1600000

  char* p = (char*)d_ws;
  auto alloc = [&](size_t bytes) -> void* {
    void* q = (void*)p;
    p += (bytes + 255) & ~(size_t)255;
    return q;
  };
  int* dflag = (int*)alloc(256);
  u16* Bsw1 = (u16*)alloc((size_t)(IN_FEATS / 32) * 8 * 64 * 8 * 2);  // 64 KB
  u16* Bsw2 = (u16*)alloc((size_t)(HID / 32) * 8 * 64 * 8 * 2);       // 32 KB
  u16* hb = (u16*)alloc((size_t)N * HID * 2);  // 25.6 MB
  u16* x = (u16*)alloc((size_t)N * HID * 2);   // 25.6 MB
  float* el = (float*)alloc((size_t)N * 4);
  float* er = (float*)alloc((size_t)N * 4);
  int* cnt8 = (int*)alloc((size_t)8 * N * 4);  // 3.2 MB (8 per-XCD replicas)
  int* indptr = (int*)alloc((size_t)(N + 1) * 4);
  int* rank = (int*)alloc((size_t)E * 4);      // 6.4 MB
  int* bsum = (int*)alloc((size_t)((N + 255) / 256) * 4);
  int* ssrc = (int*)alloc((size_t)E * 4);

  const int NB = (N + 255) / 256;     // 391 (<= 512 for scan2par)
  const int EB = (E + 255) / 256;     // 6250
  const int HEB = (E + 1023) / 1024;  // 1563 (hist: 4 edges/thread)
  const int GEMM_B = (N + 63) / 64;   // 1563
  const int NODE_B = (N + 3) / 4;     // 25000

  detect_dtype<<<1, 256, 0, stream>>>((const u32*)features, 4096, dflag);
  zero_i32<<<(8 * N + 255) / 256, 256, 0, stream>>>(cnt8, 8 * N);
  bsw_build<<<((IN_FEATS / 32) * 8 * 64 + 255) / 256, 256, 0, stream>>>(W1, Bsw1, IN_FEATS, dflag);
  bsw_build<<<((HID / 32) * 8 * 64 + 255) / 256, 256, 0, stream>>>(W2, Bsw2, HID, dflag);

  // GEMM layer 1 (+ fused el/er) co-scheduled with hist+rank (independent work)
  fused_gemm_hist<IN_FEATS, 1><<<GEMM_B + HEB, 256, 0, stream>>>(
      features, Bsw1, hb, al1, ar1, el, er, N, dflag, GEMM_B, dst, cnt8, rank, E);

  scan1<<<NB, 256, 0, stream>>>(cnt8, indptr, bsum, N);
  scan2par<<<1, 512, 0, stream>>>(bsum, NB);
  scan3<<<NB, 256, 0, stream>>>(indptr, bsum, N, E);
  scatter2<<<EB, 256, 0, stream>>>(src, dst, rank, indptr, cnt8, ssrc, E, N);

  agg_kernel<0><<<NODE_B, 256, 0, stream>>>((const u32*)hb, el, er, indptr, ssrc, b1, (void*)x, N, dflag);

  gemm_mfma<HID, 0><<<GEMM_B, 256, 0, stream>>>((const void*)x, Bsw2, hb, al2, ar2, el, er, N, dflag);
  agg_kernel<1><<<NODE_B, 256, 0, stream>>>((const u32*)hb, el, er, indptr, ssrc, b2, d_out, N, dflag);
}